// Round 3
// baseline (490.296 us; speedup 1.0000x reference)
//
#include <hip/hip_runtime.h>
#include <cstdint>
#include <math.h>

#define N_TOK 16384
#define C_DIM 2048
#define E_DIM 64
#define TILE_T 64
#define KC 64
#define EPSN 1e-12f

// scratch layout (floats): bnorm[C*E], ntok[N], denc[E]
#define SCRATCH_FLOATS (C_DIM * E_DIM + N_TOK + E_DIM)

// ---- K1a: column denominators, replicating np axis-0 sequential reduce ----
// s = sim*sim (pre-rounded mul), acc += s[k] sequentially; sqrt; max(.,eps).
__global__ __launch_bounds__(64) void coln_kernel(const float* __restrict__ sim,
                                                  float* __restrict__ denc) {
    const int e = threadIdx.x;  // one wave, lane = expert
    float acc = 0.f;
#pragma unroll 8
    for (int k = 0; k < C_DIM; ++k) {
        const float v = sim[k * E_DIM + e];
        acc = __fadd_rn(acc, __fmul_rn(v, v));
    }
    denc[e] = fmaxf(__fsqrt_rn(acc), EPSN);
}

// ---- K1b: bnorm = sim / denc (IEEE fp32 divide, matches np temp array) ----
__global__ __launch_bounds__(256) void bn_kernel(const float* __restrict__ sim,
                                                 const float* __restrict__ denc,
                                                 float* __restrict__ bnorm) {
    const int idx = blockIdx.x * 256 + threadIdx.x;   // grid covers C*E
    const int e = idx & (E_DIM - 1);
    bnorm[idx] = __fdiv_rn(sim[idx], denc[e]);
}

// ---- K2a: token denominators, replicating np PAIRWISE summation ----------
// n=2048: balanced tree over 16 leaves of 128; leaf = 8 strided accumulators
// combined ((r0+r1)+(r2+r3))+((r4+r5)+(r6+r7)). 16 lanes/token; xor butterfly
// reproduces the balanced tree (fp add commutative, association preserved).
__global__ __launch_bounds__(256) void tokn_kernel(const float* __restrict__ hs,
                                                   float* __restrict__ ntok) {
    const int t = blockIdx.x * 16 + (threadIdx.x >> 4);
    const int j = threadIdx.x & 15;                   // leaf index
    const float4* p = (const float4*)(hs + (size_t)t * C_DIM + j * 128);
    float4 v0 = p[0], v1 = p[1];
    float r0 = __fmul_rn(v0.x, v0.x), r1 = __fmul_rn(v0.y, v0.y);
    float r2 = __fmul_rn(v0.z, v0.z), r3 = __fmul_rn(v0.w, v0.w);
    float r4 = __fmul_rn(v1.x, v1.x), r5 = __fmul_rn(v1.y, v1.y);
    float r6 = __fmul_rn(v1.z, v1.z), r7 = __fmul_rn(v1.w, v1.w);
#pragma unroll
    for (int i = 2; i < 32; i += 2) {
        float4 a = p[i], b = p[i + 1];
        r0 = __fadd_rn(r0, __fmul_rn(a.x, a.x));
        r1 = __fadd_rn(r1, __fmul_rn(a.y, a.y));
        r2 = __fadd_rn(r2, __fmul_rn(a.z, a.z));
        r3 = __fadd_rn(r3, __fmul_rn(a.w, a.w));
        r4 = __fadd_rn(r4, __fmul_rn(b.x, b.x));
        r5 = __fadd_rn(r5, __fmul_rn(b.y, b.y));
        r6 = __fadd_rn(r6, __fmul_rn(b.z, b.z));
        r7 = __fadd_rn(r7, __fmul_rn(b.w, b.w));
    }
    float leaf = __fadd_rn(__fadd_rn(__fadd_rn(r0, r1), __fadd_rn(r2, r3)),
                           __fadd_rn(__fadd_rn(r4, r5), __fadd_rn(r6, r7)));
    float v = leaf;
#pragma unroll
    for (int off = 1; off <= 8; off <<= 1)
        v = __fadd_rn(v, __shfl_xor(v, off, 64));     // stays in 16-lane group
    if (j == 0) ntok[t] = fmaxf(__fsqrt_rn(v), EPSN);
}

// ---- K3: logits GEMM on normalized values, OpenBLAS sgemm structure ------
// block = 512 threads (8 waves). lane = token; wave w -> experts [8w,8w+8)
// (wave-uniform B rows -> scalar loads). A normalized during LDS staging
// (IEEE divide). K accumulated in KC=384-panel structure: sequential fma
// within panel, panels folded by plain adds (matches BLAS beta-accumulate).
__global__ __launch_bounds__(512) void logits_kernel(
        const float* __restrict__ hs, const float* __restrict__ bnorm,
        const float* __restrict__ emask, const float* __restrict__ ntok,
        float* __restrict__ out_logits) {
    __shared__ float Al[KC * 65];
    const int tid  = threadIdx.x;
    const int lane = tid & 63;
    const int w    = __builtin_amdgcn_readfirstlane(tid >> 6);  // 0..7
    const int tile = blockIdx.x * TILE_T;

    const float4* hs4 = (const float4*)hs;
    const int tok0 = tid >> 4;          // 0..31
    const int tok1 = 32 + (tid >> 4);   // 32..63
    const int q    = tid & 15;          // float4 slot within 64-float chunk
    const int rb0  = (tile + tok0) * (C_DIM / 4);
    const int rb1  = (tile + tok1) * (C_DIM / 4);
    const float dn0 = ntok[tile + tok0];
    const float dn1 = ntok[tile + tok1];

    float accT[8], accP[8];
#pragma unroll
    for (int e = 0; e < 8; ++e) { accT[e] = 0.f; accP[e] = 0.f; }

    float4 p0 = hs4[rb0 + q];
    float4 p1 = hs4[rb1 + q];

    for (int ch = 0; ch < C_DIM / KC; ++ch) {
        const int kb = 4 * q;
        Al[(kb + 0) * 65 + tok0] = __fdiv_rn(p0.x, dn0);
        Al[(kb + 1) * 65 + tok0] = __fdiv_rn(p0.y, dn0);
        Al[(kb + 2) * 65 + tok0] = __fdiv_rn(p0.z, dn0);
        Al[(kb + 3) * 65 + tok0] = __fdiv_rn(p0.w, dn0);
        Al[(kb + 0) * 65 + tok1] = __fdiv_rn(p1.x, dn1);
        Al[(kb + 1) * 65 + tok1] = __fdiv_rn(p1.y, dn1);
        Al[(kb + 2) * 65 + tok1] = __fdiv_rn(p1.z, dn1);
        Al[(kb + 3) * 65 + tok1] = __fdiv_rn(p1.w, dn1);
        __syncthreads();
        if (ch + 1 < C_DIM / KC) {      // register prefetch overlaps compute
            p0 = hs4[rb0 + (ch + 1) * (KC / 4) + q];
            p1 = hs4[rb1 + (ch + 1) * (KC / 4) + q];
        }
        const int k0 = ch * KC;
#pragma unroll 4
        for (int k = 0; k < KC; ++k) {
            const float a = Al[k * 65 + lane];
            const float* Brow = bnorm + (size_t)(k0 + k) * E_DIM + w * 8;
#pragma unroll
            for (int e = 0; e < 8; ++e) accP[e] = fmaf(a, Brow[e], accP[e]);
        }
        __syncthreads();
        // panel boundaries: after chunks 5,11,17,23,29 (k=384*p) and 31 (tail)
        if ((ch + 1) % 6 == 0 || ch == C_DIM / KC - 1) {
#pragma unroll
            for (int e = 0; e < 8; ++e) {
                accT[e] = __fadd_rn(accT[e], accP[e]);
                accP[e] = 0.f;
            }
        }
    }

    float outv[8];
#pragma unroll
    for (int e = 0; e < 8; ++e)
        outv[e] = __fmul_rn(accT[e], emask[w * 8 + e]);  // np: logits * mask
    float4* dst = (float4*)(out_logits + (size_t)(tile + lane) * E_DIM + w * 8);
    dst[0] = make_float4(outv[0], outv[1], outv[2], outv[3]);
    dst[1] = make_float4(outv[4], outv[5], outv[6], outv[7]);
}

// ---- K4: mask epilogue (threshold + top-k fallback), from MY logits -------
__global__ __launch_bounds__(256) void mask_kernel(
        const float* __restrict__ logits, const float* __restrict__ gates,
        const float* __restrict__ temp, const int* __restrict__ minkp,
        float* __restrict__ mask_out) {
    const int lane = threadIdx.x & 63;
    const int wid  = blockIdx.x * (blockDim.x >> 6) + (threadIdx.x >> 6);
    const int nw   = gridDim.x * (blockDim.x >> 6);
    const float lscale = __fdiv_rn(1.f, __fadd_rn(1.f, expf(-temp[0])));
    const float g = __fmul_rn(gates[lane], lscale);
    const int mk = *minkp;

    for (int t = wid; t < N_TOK; t += nw) {
        const float L = logits[(size_t)t * E_DIM + lane];
        const bool hard = (L - g) > 0.f;      // relu(d) > 0  <=>  d > 0
        const unsigned long long act = __ballot(hard);
        float mv;
        if (act != 0ull) {
            mv = hard ? 1.f : 0.f;
        } else {
            // top-mk of logits; ties resolve to lowest index (lax.top_k rule)
            unsigned long long chosen = 0ull;
            float Lc = L;
            for (int r = 0; r < mk; ++r) {
                float m = Lc;
                for (int o = 32; o > 0; o >>= 1) m = fmaxf(m, __shfl_xor(m, o, 64));
                const unsigned long long b = __ballot(Lc == m);
                const int idx = __ffsll((unsigned long long)b) - 1;
                chosen |= 1ull << idx;
                if (lane == idx) Lc = -INFINITY;
            }
            mv = ((chosen >> lane) & 1ull) ? 1.f : 0.f;
        }
        mask_out[(size_t)t * E_DIM + lane] = mv;
    }
}

extern "C" void kernel_launch(void* const* d_in, const int* in_sizes, int n_in,
                              void* d_out, int out_size, void* d_ws, size_t ws_size,
                              hipStream_t stream) {
    const float* hs    = (const float*)d_in[0];  // (4,4096,2048) f32
    const float* sim   = (const float*)d_in[1];  // (2048,64) f32
    const float* gates = (const float*)d_in[2];  // (64,) f32
    const float* temp  = (const float*)d_in[3];  // (1,) f32
    const float* emask = (const float*)d_in[4];  // (64,) f32
    const int*   mink  = (const int*)d_in[5];    // scalar int

    float* outm = (float*)d_out;                     // activation_mask (N*E)
    float* outl = outm + (size_t)N_TOK * E_DIM;      // logits (N*E)

    // scratch: prefer d_ws; else borrow mask region of d_out (written only by
    // the final mask_kernel -- stream-ordered, safe).
    float* scratch = (ws_size >= SCRATCH_FLOATS * sizeof(float))
                         ? (float*)d_ws : outm;
    float* bnorm = scratch;                          // C*E floats
    float* ntok  = bnorm + C_DIM * E_DIM;            // N floats
    float* denc  = ntok + N_TOK;                     // E floats

    coln_kernel<<<1, 64, 0, stream>>>(sim, denc);
    bn_kernel<<<(C_DIM * E_DIM) / 256, 256, 0, stream>>>(sim, denc, bnorm);
    tokn_kernel<<<N_TOK / 16, 256, 0, stream>>>(hs, ntok);
    logits_kernel<<<N_TOK / TILE_T, 512, 0, stream>>>(hs, bnorm, emask, ntok, outl);
    mask_kernel<<<512, 256, 0, stream>>>(outl, gates, temp, mink, outm);
}

// Round 4
// 317.011 us; speedup vs baseline: 1.5466x; 1.5466x over previous
//
#include <hip/hip_runtime.h>
#include <cstdint>
#include <math.h>

#define N_TOK 16384
#define C_DIM 2048
#define E_DIM 64
#define TILE_T 64
#define KC 64
#define EPSN 1e-12f
#define NE ((size_t)N_TOK * E_DIM)

// fast-path scratch (floats): parts[6*N*E], bnorm[C*E], ntok[N], denc[E]
#define SCRATCH_FAST (6 * N_TOK * E_DIM + C_DIM * E_DIM + N_TOK + E_DIM)
// fallback scratch (floats): bnorm[C*E], ntok[N], denc[E]
#define SCRATCH_OLD (C_DIM * E_DIM + N_TOK + E_DIM)

// ---- K1a: column denominators, np axis-0 sequential reduce (bit-exact) ----
// One block; 1024 threads stage sim through LDS (double-buffered); wave 0
// performs the exact sequential per-column fold: acc += round(v*v), k asc.
__global__ __launch_bounds__(1024) void coln_kernel(const float* __restrict__ sim,
                                                    float* __restrict__ denc) {
    __shared__ float S[2][256 * 64];     // 2 x 64 KB
    const int tid = threadIdx.x;
    {   // preload chunk 0 (rows 0..255)
        const float4* src = (const float4*)sim;
        float4* dst = (float4*)S[0];
        for (int i = tid; i < 4096; i += 1024) dst[i] = src[i];
    }
    __syncthreads();
    float acc = 0.f;
    for (int ch = 0; ch < 8; ++ch) {
        if (ch + 1 < 8) {                // stage next chunk into other buffer
            const float4* src = (const float4*)(sim + (size_t)(ch + 1) * 256 * 64);
            float4* dst = (float4*)S[(ch + 1) & 1];
            for (int i = tid; i < 4096; i += 1024) dst[i] = src[i];
        }
        if (tid < 64) {
            const float* Sc = S[ch & 1];
#pragma unroll 8
            for (int r = 0; r < 256; ++r) {
                const float v = Sc[r * 64 + tid];
                acc = __fadd_rn(acc, __fmul_rn(v, v));
            }
        }
        __syncthreads();
    }
    if (tid < 64) denc[tid] = fmaxf(__fsqrt_rn(acc), EPSN);
}

// ---- K1b: bnorm = sim / denc (IEEE fp32 divide, matches np temp array) ----
__global__ __launch_bounds__(256) void bn_kernel(const float* __restrict__ sim,
                                                 const float* __restrict__ denc,
                                                 float* __restrict__ bnorm) {
    const int idx = blockIdx.x * 256 + threadIdx.x;   // grid covers C*E
    const int e = idx & (E_DIM - 1);
    bnorm[idx] = __fdiv_rn(sim[idx], denc[e]);
}

// ---- K2: token denominators, np PAIRWISE summation (bit-exact) -----------
__global__ __launch_bounds__(256) void tokn_kernel(const float* __restrict__ hs,
                                                   float* __restrict__ ntok) {
    const int t = blockIdx.x * 16 + (threadIdx.x >> 4);
    const int j = threadIdx.x & 15;                   // leaf index (128 floats)
    const float4* p = (const float4*)(hs + (size_t)t * C_DIM + j * 128);
    float4 v0 = p[0], v1 = p[1];
    float r0 = __fmul_rn(v0.x, v0.x), r1 = __fmul_rn(v0.y, v0.y);
    float r2 = __fmul_rn(v0.z, v0.z), r3 = __fmul_rn(v0.w, v0.w);
    float r4 = __fmul_rn(v1.x, v1.x), r5 = __fmul_rn(v1.y, v1.y);
    float r6 = __fmul_rn(v1.z, v1.z), r7 = __fmul_rn(v1.w, v1.w);
#pragma unroll
    for (int i = 2; i < 32; i += 2) {
        float4 a = p[i], b = p[i + 1];
        r0 = __fadd_rn(r0, __fmul_rn(a.x, a.x));
        r1 = __fadd_rn(r1, __fmul_rn(a.y, a.y));
        r2 = __fadd_rn(r2, __fmul_rn(a.z, a.z));
        r3 = __fadd_rn(r3, __fmul_rn(a.w, a.w));
        r4 = __fadd_rn(r4, __fmul_rn(b.x, b.x));
        r5 = __fadd_rn(r5, __fmul_rn(b.y, b.y));
        r6 = __fadd_rn(r6, __fmul_rn(b.z, b.z));
        r7 = __fadd_rn(r7, __fmul_rn(b.w, b.w));
    }
    float leaf = __fadd_rn(__fadd_rn(__fadd_rn(r0, r1), __fadd_rn(r2, r3)),
                           __fadd_rn(__fadd_rn(r4, r5), __fadd_rn(r6, r7)));
    float v = leaf;
#pragma unroll
    for (int off = 1; off <= 8; off <<= 1)
        v = __fadd_rn(v, __shfl_xor(v, off, 64));     // balanced 16-leaf tree
    if (j == 0) ntok[t] = fmaxf(__fsqrt_rn(v), EPSN);
}

// ---- K3 (fast): one OpenBLAS 384-k panel per block -> partial sums -------
// grid (256 token-tiles, 6 panels). block = 512 threads (8 waves); lane =
// token, wave w -> experts [8w,8w+8) (wave-uniform B rows -> s_load).
// LDS A[token][68]: ds_write_b128 staging, ds_read_b128 row reads, both
// conflict-free (start bank 4*(lane+k) % 32). Within-panel order: sequential
// fmaf over ascending k — bit-identical to the verified round-3 kernel.
__global__ __launch_bounds__(512) void logits_split_kernel(
        const float* __restrict__ hs, const float* __restrict__ bnorm,
        const float* __restrict__ ntok, float* __restrict__ parts) {
    __shared__ float As[TILE_T * 68];
    const int tid  = threadIdx.x;
    const int lane = tid & 63;
    const int w    = __builtin_amdgcn_readfirstlane(tid >> 6);  // 0..7
    const int tile = blockIdx.x * TILE_T;
    const int s    = blockIdx.y;                                // panel id
    const int cbeg = s * 6;
    const int cend = (cbeg + 6 < 32) ? cbeg + 6 : 32;           // panel 5: 2 chunks

    const float4* hs4 = (const float4*)hs;
    const int tok0 = tid >> 4;          // 0..31
    const int tok1 = 32 + (tid >> 4);   // 32..63
    const int q    = tid & 15;          // float4 slot within 64-float chunk
    const int rb0  = (tile + tok0) * (C_DIM / 4);
    const int rb1  = (tile + tok1) * (C_DIM / 4);
    const float dn0 = ntok[tile + tok0];
    const float dn1 = ntok[tile + tok1];

    float acc[8];
#pragma unroll
    for (int e = 0; e < 8; ++e) acc[e] = 0.f;

    float4 p0 = hs4[rb0 + cbeg * 16 + q];
    float4 p1 = hs4[rb1 + cbeg * 16 + q];

    for (int ch = cbeg; ch < cend; ++ch) {
        float4 n0, n1;
        n0.x = __fdiv_rn(p0.x, dn0); n0.y = __fdiv_rn(p0.y, dn0);
        n0.z = __fdiv_rn(p0.z, dn0); n0.w = __fdiv_rn(p0.w, dn0);
        n1.x = __fdiv_rn(p1.x, dn1); n1.y = __fdiv_rn(p1.y, dn1);
        n1.z = __fdiv_rn(p1.z, dn1); n1.w = __fdiv_rn(p1.w, dn1);
        *(float4*)&As[tok0 * 68 + 4 * q] = n0;    // ds_write_b128
        *(float4*)&As[tok1 * 68 + 4 * q] = n1;
        __syncthreads();
        if (ch + 1 < cend) {            // register prefetch overlaps compute
            p0 = hs4[rb0 + (ch + 1) * 16 + q];
            p1 = hs4[rb1 + (ch + 1) * 16 + q];
        }
        const int k0 = ch * KC;
#pragma unroll
        for (int k4 = 0; k4 < 16; ++k4) {
            const float4 a4 = *(const float4*)&As[lane * 68 + 4 * k4];  // b128
            const float* ac = (const float*)&a4;
            const float* Brow = bnorm + (size_t)(k0 + 4 * k4) * E_DIM + w * 8;
#pragma unroll
            for (int c = 0; c < 4; ++c) {
                const float a = ac[c];
#pragma unroll
                for (int e = 0; e < 8; ++e)
                    acc[e] = fmaf(a, Brow[c * E_DIM + e], acc[e]);
            }
        }
        __syncthreads();
    }

    float4* dst = (float4*)(parts + (size_t)s * NE +
                            (size_t)(tile + lane) * E_DIM + w * 8);
    dst[0] = make_float4(acc[0], acc[1], acc[2], acc[3]);
    dst[1] = make_float4(acc[4], acc[5], acc[6], acc[7]);
}

// ---- K4 (fast): exact left-fold of panels + emask + threshold + top-k ----
__global__ __launch_bounds__(256) void epilogue_kernel(
        const float* __restrict__ parts, const float* __restrict__ gates,
        const float* __restrict__ temp, const float* __restrict__ emask,
        const int* __restrict__ minkp, float* __restrict__ mask_out,
        float* __restrict__ logits_out) {
    const int lane = threadIdx.x & 63;
    const int wid  = blockIdx.x * (blockDim.x >> 6) + (threadIdx.x >> 6);
    const int nw   = gridDim.x * (blockDim.x >> 6);
    const float lscale = __fdiv_rn(1.f, __fadd_rn(1.f, expf(-temp[0])));
    const float g  = __fmul_rn(gates[lane], lscale);
    const float em = emask[lane];
    const int mk = *minkp;

    for (int t = wid; t < N_TOK; t += nw) {
        const size_t idx = (size_t)t * E_DIM + lane;
        float L = parts[idx];                         // p0
#pragma unroll
        for (int s = 1; s < 6; ++s)                   // ((((p0+p1)+p2)+p3)+p4)+p5
            L = __fadd_rn(L, parts[(size_t)s * NE + idx]);
        L = __fmul_rn(L, em);
        logits_out[idx] = L;

        const bool hard = (L - g) > 0.f;
        const unsigned long long act = __ballot(hard);
        float mv;
        if (act != 0ull) {
            mv = hard ? 1.f : 0.f;
        } else {
            unsigned long long chosen = 0ull;
            float Lc = L;
            for (int r = 0; r < mk; ++r) {
                float m = Lc;
                for (int o = 32; o > 0; o >>= 1) m = fmaxf(m, __shfl_xor(m, o, 64));
                const unsigned long long b = __ballot(Lc == m);
                const int ix = __ffsll((unsigned long long)b) - 1;
                chosen |= 1ull << ix;
                if (lane == ix) Lc = -INFINITY;
            }
            mv = ((chosen >> lane) & 1ull) ? 1.f : 0.f;
        }
        mask_out[idx] = mv;
    }
}

// ================= fallback path (round-3, verified) ======================
__global__ __launch_bounds__(512) void logits_kernel_old(
        const float* __restrict__ hs, const float* __restrict__ bnorm,
        const float* __restrict__ emask, const float* __restrict__ ntok,
        float* __restrict__ out_logits) {
    __shared__ float Al[KC * 65];
    const int tid  = threadIdx.x;
    const int lane = tid & 63;
    const int w    = __builtin_amdgcn_readfirstlane(tid >> 6);
    const int tile = blockIdx.x * TILE_T;
    const float4* hs4 = (const float4*)hs;
    const int tok0 = tid >> 4;
    const int tok1 = 32 + (tid >> 4);
    const int q    = tid & 15;
    const int rb0  = (tile + tok0) * (C_DIM / 4);
    const int rb1  = (tile + tok1) * (C_DIM / 4);
    const float dn0 = ntok[tile + tok0];
    const float dn1 = ntok[tile + tok1];
    float accT[8], accP[8];
#pragma unroll
    for (int e = 0; e < 8; ++e) { accT[e] = 0.f; accP[e] = 0.f; }
    float4 p0 = hs4[rb0 + q];
    float4 p1 = hs4[rb1 + q];
    for (int ch = 0; ch < C_DIM / KC; ++ch) {
        const int kb = 4 * q;
        Al[(kb + 0) * 65 + tok0] = __fdiv_rn(p0.x, dn0);
        Al[(kb + 1) * 65 + tok0] = __fdiv_rn(p0.y, dn0);
        Al[(kb + 2) * 65 + tok0] = __fdiv_rn(p0.z, dn0);
        Al[(kb + 3) * 65 + tok0] = __fdiv_rn(p0.w, dn0);
        Al[(kb + 0) * 65 + tok1] = __fdiv_rn(p1.x, dn1);
        Al[(kb + 1) * 65 + tok1] = __fdiv_rn(p1.y, dn1);
        Al[(kb + 2) * 65 + tok1] = __fdiv_rn(p1.z, dn1);
        Al[(kb + 3) * 65 + tok1] = __fdiv_rn(p1.w, dn1);
        __syncthreads();
        if (ch + 1 < C_DIM / KC) {
            p0 = hs4[rb0 + (ch + 1) * (KC / 4) + q];
            p1 = hs4[rb1 + (ch + 1) * (KC / 4) + q];
        }
        const int k0 = ch * KC;
#pragma unroll 4
        for (int k = 0; k < KC; ++k) {
            const float a = Al[k * 65 + lane];
            const float* Brow = bnorm + (size_t)(k0 + k) * E_DIM + w * 8;
#pragma unroll
            for (int e = 0; e < 8; ++e) accP[e] = fmaf(a, Brow[e], accP[e]);
        }
        __syncthreads();
        if ((ch + 1) % 6 == 0 || ch == C_DIM / KC - 1) {
#pragma unroll
            for (int e = 0; e < 8; ++e) {
                accT[e] = __fadd_rn(accT[e], accP[e]);
                accP[e] = 0.f;
            }
        }
    }
    float outv[8];
#pragma unroll
    for (int e = 0; e < 8; ++e)
        outv[e] = __fmul_rn(accT[e], emask[w * 8 + e]);
    float4* dst = (float4*)(out_logits + (size_t)(tile + lane) * E_DIM + w * 8);
    dst[0] = make_float4(outv[0], outv[1], outv[2], outv[3]);
    dst[1] = make_float4(outv[4], outv[5], outv[6], outv[7]);
}

__global__ __launch_bounds__(256) void mask_kernel_old(
        const float* __restrict__ logits, const float* __restrict__ gates,
        const float* __restrict__ temp, const int* __restrict__ minkp,
        float* __restrict__ mask_out) {
    const int lane = threadIdx.x & 63;
    const int wid  = blockIdx.x * (blockDim.x >> 6) + (threadIdx.x >> 6);
    const int nw   = gridDim.x * (blockDim.x >> 6);
    const float lscale = __fdiv_rn(1.f, __fadd_rn(1.f, expf(-temp[0])));
    const float g = __fmul_rn(gates[lane], lscale);
    const int mk = *minkp;
    for (int t = wid; t < N_TOK; t += nw) {
        const float L = logits[(size_t)t * E_DIM + lane];
        const bool hard = (L - g) > 0.f;
        const unsigned long long act = __ballot(hard);
        float mv;
        if (act != 0ull) {
            mv = hard ? 1.f : 0.f;
        } else {
            unsigned long long chosen = 0ull;
            float Lc = L;
            for (int r = 0; r < mk; ++r) {
                float m = Lc;
                for (int o = 32; o > 0; o >>= 1) m = fmaxf(m, __shfl_xor(m, o, 64));
                const unsigned long long b = __ballot(Lc == m);
                const int ix = __ffsll((unsigned long long)b) - 1;
                chosen |= 1ull << ix;
                if (lane == ix) Lc = -INFINITY;
            }
            mv = ((chosen >> lane) & 1ull) ? 1.f : 0.f;
        }
        mask_out[(size_t)t * E_DIM + lane] = mv;
    }
}

extern "C" void kernel_launch(void* const* d_in, const int* in_sizes, int n_in,
                              void* d_out, int out_size, void* d_ws, size_t ws_size,
                              hipStream_t stream) {
    const float* hs    = (const float*)d_in[0];  // (4,4096,2048) f32
    const float* sim   = (const float*)d_in[1];  // (2048,64) f32
    const float* gates = (const float*)d_in[2];  // (64,) f32
    const float* temp  = (const float*)d_in[3];  // (1,) f32
    const float* emask = (const float*)d_in[4];  // (64,) f32
    const int*   mink  = (const int*)d_in[5];    // scalar int

    float* outm = (float*)d_out;                     // activation_mask (N*E)
    float* outl = outm + NE;                         // logits (N*E)

    if (ws_size >= (size_t)SCRATCH_FAST * sizeof(float)) {
        float* parts = (float*)d_ws;                 // 6*N*E
        float* bnorm = parts + 6 * NE;               // C*E
        float* ntok  = bnorm + C_DIM * E_DIM;        // N
        float* denc  = ntok + N_TOK;                 // E

        coln_kernel<<<1, 1024, 0, stream>>>(sim, denc);
        bn_kernel<<<(C_DIM * E_DIM) / 256, 256, 0, stream>>>(sim, denc, bnorm);
        tokn_kernel<<<N_TOK / 16, 256, 0, stream>>>(hs, ntok);
        logits_split_kernel<<<dim3(N_TOK / TILE_T, 6), 512, 0, stream>>>(
            hs, bnorm, ntok, parts);
        epilogue_kernel<<<1024, 256, 0, stream>>>(parts, gates, temp, emask,
                                                  mink, outm, outl);
    } else {
        float* scratch = (ws_size >= (size_t)SCRATCH_OLD * sizeof(float))
                             ? (float*)d_ws : outm;
        float* bnorm = scratch;
        float* ntok  = bnorm + C_DIM * E_DIM;
        float* denc  = ntok + N_TOK;
        coln_kernel<<<1, 1024, 0, stream>>>(sim, denc);
        bn_kernel<<<(C_DIM * E_DIM) / 256, 256, 0, stream>>>(sim, denc, bnorm);
        tokn_kernel<<<N_TOK / 16, 256, 0, stream>>>(hs, ntok);
        logits_kernel_old<<<N_TOK / TILE_T, 512, 0, stream>>>(hs, bnorm, emask,
                                                              ntok, outl);
        mask_kernel_old<<<512, 256, 0, stream>>>(outl, gates, temp, mink, outm);
    }
}

// Round 5
// 309.837 us; speedup vs baseline: 1.5824x; 1.0232x over previous
//
#include <hip/hip_runtime.h>
#include <cstdint>
#include <math.h>

#define N_TOK 16384
#define C_DIM 2048
#define E_DIM 64
#define TILE_T 64
#define KC 64
#define EPSN 1e-12f
#define NE ((size_t)N_TOK * E_DIM)

// fast-path scratch (floats): parts[6*N*E], bnorm[C*E], ntok[N], denc[E]
#define SCRATCH_FAST (6 * N_TOK * E_DIM + C_DIM * E_DIM + N_TOK + E_DIM)
// fallback scratch (floats): bnorm[C*E], ntok[N], denc[E]
#define SCRATCH_OLD (C_DIM * E_DIM + N_TOK + E_DIM)

// ---- K1a: column denominators, np axis-0 sequential reduce (bit-exact) ----
__global__ __launch_bounds__(1024) void coln_kernel(const float* __restrict__ sim,
                                                    float* __restrict__ denc) {
    __shared__ float S[2][256 * 64];     // 2 x 64 KB
    const int tid = threadIdx.x;
    {   // preload chunk 0 (rows 0..255)
        const float4* src = (const float4*)sim;
        float4* dst = (float4*)S[0];
        for (int i = tid; i < 4096; i += 1024) dst[i] = src[i];
    }
    __syncthreads();
    float acc = 0.f;
    for (int ch = 0; ch < 8; ++ch) {
        if (ch + 1 < 8) {                // stage next chunk into other buffer
            const float4* src = (const float4*)(sim + (size_t)(ch + 1) * 256 * 64);
            float4* dst = (float4*)S[(ch + 1) & 1];
            for (int i = tid; i < 4096; i += 1024) dst[i] = src[i];
        }
        if (tid < 64) {
            const float* Sc = S[ch & 1];
#pragma unroll 8
            for (int r = 0; r < 256; ++r) {
                const float v = Sc[r * 64 + tid];
                acc = __fadd_rn(acc, __fmul_rn(v, v));
            }
        }
        __syncthreads();
    }
    if (tid < 64) denc[tid] = fmaxf(__fsqrt_rn(acc), EPSN);
}

// ---- K1b: bnorm = sim / denc (IEEE fp32 divide, matches np temp array) ----
__global__ __launch_bounds__(256) void bn_kernel(const float* __restrict__ sim,
                                                 const float* __restrict__ denc,
                                                 float* __restrict__ bnorm) {
    const int idx = blockIdx.x * 256 + threadIdx.x;   // grid covers C*E
    const int e = idx & (E_DIM - 1);
    bnorm[idx] = __fdiv_rn(sim[idx], denc[e]);
}

// ---- K2: token denominators, np PAIRWISE summation (bit-exact) -----------
// 4 tokens/block staged into LDS via coalesced float4 loads (leaf stride
// padded 128->132 words). Thread = (token=wave, leaf j, quarter qd): two
// 16-term chains r_{2qd}, r_{2qd+1}; combine qd via shfl_xor 1,2 then the
// balanced 16-leaf tree via shfl_xor 4,8,16,32 — association identical to
// numpy pairwise_sum (verified structure from round 3).
__global__ __launch_bounds__(256) void tokn_kernel(const float* __restrict__ hs,
                                                   float* __restrict__ ntok) {
    __shared__ float X[4 * 2112];
    const int tid  = threadIdx.x;
    const int tblk = blockIdx.x * 4;
    const float4* src = (const float4*)(hs + (size_t)tblk * C_DIM);
#pragma unroll
    for (int it = 0; it < 8; ++it) {
        const int g   = it * 256 + tid;   // 0..2047 float4 slots
        const float4 v = src[g];
        const int tok = g >> 9;           // 512 float4 per token
        const int f   = g & 511;
        const int j   = f >> 5;           // leaf (32 float4 per leaf)
        const int r4  = f & 31;
        *(float4*)&X[tok * 2112 + j * 132 + r4 * 4] = v;
    }
    __syncthreads();
    const int tok = tid >> 6;             // wave = token
    const int j   = (tid >> 2) & 15;
    const int qd  = tid & 3;
    float ra = 0.f, rb = 0.f;
#pragma unroll
    for (int i = 0; i < 16; ++i) {
        const float2 v = *(const float2*)&X[tok * 2112 + j * 132 + 8 * i + 2 * qd];
        ra = __fadd_rn(ra, __fmul_rn(v.x, v.x));   // r_{2qd}
        rb = __fadd_rn(rb, __fmul_rn(v.y, v.y));   // r_{2qd+1}
    }
    float v = __fadd_rn(ra, rb);                   // s_qd
    v = __fadd_rn(v, __shfl_xor(v, 1, 64));        // (s0+s1),(s2+s3)
    v = __fadd_rn(v, __shfl_xor(v, 2, 64));        // leaf j
    v = __fadd_rn(v, __shfl_xor(v, 4, 64));        // 16-leaf balanced tree
    v = __fadd_rn(v, __shfl_xor(v, 8, 64));
    v = __fadd_rn(v, __shfl_xor(v, 16, 64));
    v = __fadd_rn(v, __shfl_xor(v, 32, 64));
    if ((tid & 63) == 0) ntok[tblk + tok] = fmaxf(__fsqrt_rn(v), EPSN);
}

// ---- K3 (fast): one OpenBLAS 384-k panel per block -> partial sums -------
// grid (256 tiles, 6 panels) x 256 threads (4 waves) = exactly 6 blocks/CU,
// single dispatch round, 24 waves/CU. lane = token; wave w -> experts
// [16w,16w+16) (wave-uniform B -> s_load / SGPR-sourced v_fmac). Per-(t,e)
// numerics: sequential fmaf over ascending k within panel — bit-identical.
__global__ __launch_bounds__(256) void logits_split_kernel(
        const float* __restrict__ hs, const float* __restrict__ bnorm,
        const float* __restrict__ ntok, float* __restrict__ parts) {
    __shared__ float As[TILE_T * 68];
    const int tid  = threadIdx.x;
    const int lane = tid & 63;
    const int w    = __builtin_amdgcn_readfirstlane(tid >> 6);  // 0..3
    const int tile = blockIdx.x * TILE_T;
    const int s    = blockIdx.y;                                // panel id
    const int cbeg = s * 6;
    const int cend = (cbeg + 6 < 32) ? cbeg + 6 : 32;           // panel 5: 2 chunks

    const float4* hs4 = (const float4*)hs;
    const int q  = tid & 15;            // float4 slot within 64-float chunk
    const int r0 = tid >> 4;            // 0..15; rows r0+16j
    int   rb[4];
    float dn[4];
#pragma unroll
    for (int jj = 0; jj < 4; ++jj) {
        rb[jj] = (tile + r0 + 16 * jj) * (C_DIM / 4);
        dn[jj] = ntok[tile + r0 + 16 * jj];
    }

    float acc[16];
#pragma unroll
    for (int e = 0; e < 16; ++e) acc[e] = 0.f;

    float4 p[4];
#pragma unroll
    for (int jj = 0; jj < 4; ++jj) p[jj] = hs4[rb[jj] + cbeg * 16 + q];

    for (int ch = cbeg; ch < cend; ++ch) {
#pragma unroll
        for (int jj = 0; jj < 4; ++jj) {
            float4 n;
            n.x = __fdiv_rn(p[jj].x, dn[jj]);
            n.y = __fdiv_rn(p[jj].y, dn[jj]);
            n.z = __fdiv_rn(p[jj].z, dn[jj]);
            n.w = __fdiv_rn(p[jj].w, dn[jj]);
            *(float4*)&As[(r0 + 16 * jj) * 68 + 4 * q] = n;   // ds_write_b128
        }
        __syncthreads();
        if (ch + 1 < cend) {            // register prefetch overlaps compute
#pragma unroll
            for (int jj = 0; jj < 4; ++jj)
                p[jj] = hs4[rb[jj] + (ch + 1) * 16 + q];
        }
        const int k0 = ch * KC;
#pragma unroll
        for (int k4 = 0; k4 < 16; ++k4) {
            const float4 a4 = *(const float4*)&As[lane * 68 + 4 * k4];  // b128
            const float* ac = (const float*)&a4;
            const float* Brow = bnorm + (size_t)(k0 + 4 * k4) * E_DIM + w * 16;
#pragma unroll
            for (int c = 0; c < 4; ++c) {
                const float a = ac[c];
#pragma unroll
                for (int e = 0; e < 16; ++e)
                    acc[e] = fmaf(a, Brow[c * E_DIM + e], acc[e]);
            }
        }
        __syncthreads();
    }

    float4* dst = (float4*)(parts + (size_t)s * NE +
                            (size_t)(tile + lane) * E_DIM + w * 16);
    dst[0] = make_float4(acc[0],  acc[1],  acc[2],  acc[3]);
    dst[1] = make_float4(acc[4],  acc[5],  acc[6],  acc[7]);
    dst[2] = make_float4(acc[8],  acc[9],  acc[10], acc[11]);
    dst[3] = make_float4(acc[12], acc[13], acc[14], acc[15]);
}

// ---- K4 (fast): exact left-fold of panels + emask + threshold + top-k ----
__global__ __launch_bounds__(256) void epilogue_kernel(
        const float* __restrict__ parts, const float* __restrict__ gates,
        const float* __restrict__ temp, const float* __restrict__ emask,
        const int* __restrict__ minkp, float* __restrict__ mask_out,
        float* __restrict__ logits_out) {
    const int lane = threadIdx.x & 63;
    const int wid  = blockIdx.x * (blockDim.x >> 6) + (threadIdx.x >> 6);
    const int nw   = gridDim.x * (blockDim.x >> 6);
    const float lscale = __fdiv_rn(1.f, __fadd_rn(1.f, expf(-temp[0])));
    const float g  = __fmul_rn(gates[lane], lscale);
    const float em = emask[lane];
    const int mk = *minkp;

    for (int t = wid; t < N_TOK; t += nw) {
        const size_t idx = (size_t)t * E_DIM + lane;
        float L = parts[idx];                         // p0
#pragma unroll
        for (int s = 1; s < 6; ++s)                   // ((((p0+p1)+p2)+p3)+p4)+p5
            L = __fadd_rn(L, parts[(size_t)s * NE + idx]);
        L = __fmul_rn(L, em);
        logits_out[idx] = L;

        const bool hard = (L - g) > 0.f;
        const unsigned long long act = __ballot(hard);
        float mv;
        if (act != 0ull) {
            mv = hard ? 1.f : 0.f;
        } else {
            unsigned long long chosen = 0ull;
            float Lc = L;
            for (int r = 0; r < mk; ++r) {
                float m = Lc;
                for (int o = 32; o > 0; o >>= 1) m = fmaxf(m, __shfl_xor(m, o, 64));
                const unsigned long long b = __ballot(Lc == m);
                const int ix = __ffsll((unsigned long long)b) - 1;
                chosen |= 1ull << ix;
                if (lane == ix) Lc = -INFINITY;
            }
            mv = ((chosen >> lane) & 1ull) ? 1.f : 0.f;
        }
        mask_out[idx] = mv;
    }
}

// ================= fallback path (round-3, verified) ======================
__global__ __launch_bounds__(512) void logits_kernel_old(
        const float* __restrict__ hs, const float* __restrict__ bnorm,
        const float* __restrict__ emask, const float* __restrict__ ntok,
        float* __restrict__ out_logits) {
    __shared__ float Al[KC * 65];
    const int tid  = threadIdx.x;
    const int lane = tid & 63;
    const int w    = __builtin_amdgcn_readfirstlane(tid >> 6);
    const int tile = blockIdx.x * TILE_T;
    const float4* hs4 = (const float4*)hs;
    const int tok0 = tid >> 4;
    const int tok1 = 32 + (tid >> 4);
    const int q    = tid & 15;
    const int rb0  = (tile + tok0) * (C_DIM / 4);
    const int rb1  = (tile + tok1) * (C_DIM / 4);
    const float dn0 = ntok[tile + tok0];
    const float dn1 = ntok[tile + tok1];
    float accT[8], accP[8];
#pragma unroll
    for (int e = 0; e < 8; ++e) { accT[e] = 0.f; accP[e] = 0.f; }
    float4 p0 = hs4[rb0 + q];
    float4 p1 = hs4[rb1 + q];
    for (int ch = 0; ch < C_DIM / KC; ++ch) {
        const int kb = 4 * q;
        Al[(kb + 0) * 65 + tok0] = __fdiv_rn(p0.x, dn0);
        Al[(kb + 1) * 65 + tok0] = __fdiv_rn(p0.y, dn0);
        Al[(kb + 2) * 65 + tok0] = __fdiv_rn(p0.z, dn0);
        Al[(kb + 3) * 65 + tok0] = __fdiv_rn(p0.w, dn0);
        Al[(kb + 0) * 65 + tok1] = __fdiv_rn(p1.x, dn1);
        Al[(kb + 1) * 65 + tok1] = __fdiv_rn(p1.y, dn1);
        Al[(kb + 2) * 65 + tok1] = __fdiv_rn(p1.z, dn1);
        Al[(kb + 3) * 65 + tok1] = __fdiv_rn(p1.w, dn1);
        __syncthreads();
        if (ch + 1 < C_DIM / KC) {
            p0 = hs4[rb0 + (ch + 1) * (KC / 4) + q];
            p1 = hs4[rb1 + (ch + 1) * (KC / 4) + q];
        }
        const int k0 = ch * KC;
#pragma unroll 4
        for (int k = 0; k < KC; ++k) {
            const float a = Al[k * 65 + lane];
            const float* Brow = bnorm + (size_t)(k0 + k) * E_DIM + w * 8;
#pragma unroll
            for (int e = 0; e < 8; ++e) accP[e] = fmaf(a, Brow[e], accP[e]);
        }
        __syncthreads();
        if ((ch + 1) % 6 == 0 || ch == C_DIM / KC - 1) {
#pragma unroll
            for (int e = 0; e < 8; ++e) {
                accT[e] = __fadd_rn(accT[e], accP[e]);
                accP[e] = 0.f;
            }
        }
    }
    float outv[8];
#pragma unroll
    for (int e = 0; e < 8; ++e)
        outv[e] = __fmul_rn(accT[e], emask[w * 8 + e]);
    float4* dst = (float4*)(out_logits + (size_t)(tile + lane) * E_DIM + w * 8);
    dst[0] = make_float4(outv[0], outv[1], outv[2], outv[3]);
    dst[1] = make_float4(outv[4], outv[5], outv[6], outv[7]);
}

__global__ __launch_bounds__(256) void mask_kernel_old(
        const float* __restrict__ logits, const float* __restrict__ gates,
        const float* __restrict__ temp, const int* __restrict__ minkp,
        float* __restrict__ mask_out) {
    const int lane = threadIdx.x & 63;
    const int wid  = blockIdx.x * (blockDim.x >> 6) + (threadIdx.x >> 6);
    const int nw   = gridDim.x * (blockDim.x >> 6);
    const float lscale = __fdiv_rn(1.f, __fadd_rn(1.f, expf(-temp[0])));
    const float g = __fmul_rn(gates[lane], lscale);
    const int mk = *minkp;
    for (int t = wid; t < N_TOK; t += nw) {
        const float L = logits[(size_t)t * E_DIM + lane];
        const bool hard = (L - g) > 0.f;
        const unsigned long long act = __ballot(hard);
        float mv;
        if (act != 0ull) {
            mv = hard ? 1.f : 0.f;
        } else {
            unsigned long long chosen = 0ull;
            float Lc = L;
            for (int r = 0; r < mk; ++r) {
                float m = Lc;
                for (int o = 32; o > 0; o >>= 1) m = fmaxf(m, __shfl_xor(m, o, 64));
                const unsigned long long b = __ballot(Lc == m);
                const int ix = __ffsll((unsigned long long)b) - 1;
                chosen |= 1ull << ix;
                if (lane == ix) Lc = -INFINITY;
            }
            mv = ((chosen >> lane) & 1ull) ? 1.f : 0.f;
        }
        mask_out[(size_t)t * E_DIM + lane] = mv;
    }
}

extern "C" void kernel_launch(void* const* d_in, const int* in_sizes, int n_in,
                              void* d_out, int out_size, void* d_ws, size_t ws_size,
                              hipStream_t stream) {
    const float* hs    = (const float*)d_in[0];  // (4,4096,2048) f32
    const float* sim   = (const float*)d_in[1];  // (2048,64) f32
    const float* gates = (const float*)d_in[2];  // (64,) f32
    const float* temp  = (const float*)d_in[3];  // (1,) f32
    const float* emask = (const float*)d_in[4];  // (64,) f32
    const int*   mink  = (const int*)d_in[5];    // scalar int

    float* outm = (float*)d_out;                     // activation_mask (N*E)
    float* outl = outm + NE;                         // logits (N*E)

    if (ws_size >= (size_t)SCRATCH_FAST * sizeof(float)) {
        float* parts = (float*)d_ws;                 // 6*N*E
        float* bnorm = parts + 6 * NE;               // C*E
        float* ntok  = bnorm + C_DIM * E_DIM;        // N
        float* denc  = ntok + N_TOK;                 // E

        coln_kernel<<<1, 1024, 0, stream>>>(sim, denc);
        bn_kernel<<<(C_DIM * E_DIM) / 256, 256, 0, stream>>>(sim, denc, bnorm);
        tokn_kernel<<<N_TOK / 4, 256, 0, stream>>>(hs, ntok);
        logits_split_kernel<<<dim3(N_TOK / TILE_T, 6), 256, 0, stream>>>(
            hs, bnorm, ntok, parts);
        epilogue_kernel<<<1024, 256, 0, stream>>>(parts, gates, temp, emask,
                                                  mink, outm, outl);
    } else {
        float* scratch = (ws_size >= (size_t)SCRATCH_OLD * sizeof(float))
                             ? (float*)d_ws : outm;
        float* bnorm = scratch;
        float* ntok  = bnorm + C_DIM * E_DIM;
        float* denc  = ntok + N_TOK;
        coln_kernel<<<1, 1024, 0, stream>>>(sim, denc);
        bn_kernel<<<(C_DIM * E_DIM) / 256, 256, 0, stream>>>(sim, denc, bnorm);
        tokn_kernel<<<N_TOK / 4, 256, 0, stream>>>(hs, ntok);
        logits_kernel_old<<<N_TOK / TILE_T, 512, 0, stream>>>(hs, bnorm, emask,
                                                              ntok, outl);
        mask_kernel_old<<<512, 256, 0, stream>>>(outl, gates, temp, mink, outm);
    }
}